// Round 1
// baseline (532.852 us; speedup 1.0000x reference)
//
#include <hip/hip_runtime.h>
#include <cstdint>
#include <cstddef>

#define B_ 64
#define P_ 24564
#define C_ 21
#define N_ 16
#define THRESH_ 0.5f

// ---------------------------------------------------------------- helpers

__device__ inline unsigned long long shfl_down_u64(unsigned long long v, int off) {
    unsigned lo = (unsigned)(v & 0xFFFFFFFFull);
    unsigned hi = (unsigned)(v >> 32);
    lo = __shfl_down(lo, off);
    hi = __shfl_down(hi, off);
    return ((unsigned long long)hi << 32) | lo;
}

// IoU between a corner-form truth box and a corner-form prior box.
// Mirrors the reference arithmetic exactly (areas from corner diffs).
__device__ inline float iou_corner(float tx1, float ty1, float tx2, float ty2,
                                   float px1, float py1, float px2, float py2) {
    float lx = fmaxf(tx1, px1), ly = fmaxf(ty1, py1);
    float rx = fminf(tx2, px2), ry = fminf(ty2, py2);
    float w = fmaxf(rx - lx, 0.0f), h = fmaxf(ry - ly, 0.0f);
    float inter = w * h;
    float at = (tx2 - tx1) * (ty2 - ty1);
    float ap = (px2 - px1) * (py2 - py1);
    return inter / (at + ap - inter);
}

// ---------------------------------------------------------------- kernels

// K0: zero accumulators + per-batch positive counts (ws is poisoned 0xAA).
__global__ void k0_init(double* __restrict__ acc, int* __restrict__ numpos) {
    int t = threadIdx.x;
    if (t < 2) acc[t] = 0.0;
    if (t < B_) numpos[t] = 0;
}

// K2: per (b, p): best truth over N=16 (first-max tie-break via strict >),
// packed byte: low 4 bits = best_truth_idx, bit 4 = (iou >= 0.5).
__global__ void k2_match(const float* __restrict__ priors,
                         const float* __restrict__ truths,
                         uint8_t* __restrict__ match) {
    int b = blockIdx.y;
    int p = blockIdx.x * blockDim.x + threadIdx.x;
    __shared__ float tr[N_ * 4];
    if (threadIdx.x < N_ * 4) tr[threadIdx.x] = truths[b * N_ * 4 + threadIdx.x];
    __syncthreads();
    if (p >= P_) return;

    float4 pr = ((const float4*)priors)[p];
    float px1 = pr.x - pr.z * 0.5f, py1 = pr.y - pr.w * 0.5f;
    float px2 = pr.x + pr.z * 0.5f, py2 = pr.y + pr.w * 0.5f;

    float best = -1.0f;
    int bn = 0;
#pragma unroll
    for (int n = 0; n < N_; n++) {
        float iou = iou_corner(tr[n * 4 + 0], tr[n * 4 + 1], tr[n * 4 + 2], tr[n * 4 + 3],
                               px1, py1, px2, py2);
        if (iou > best) { best = iou; bn = n; }
    }
    match[(size_t)b * P_ + p] = (uint8_t)(bn | ((best < THRESH_) ? 0 : 0x10));
}

// K3: per (b, n): argmax over P priors of IoU (first-max tie -> smallest p).
// One block per (b,n); key = (iou_bits << 32) | ~p, reduce max.
__global__ void k3_bestprior(const float* __restrict__ priors,
                             const float* __restrict__ truths,
                             int* __restrict__ bpi) {
    int b = blockIdx.x / N_;
    int n = blockIdx.x % N_;
    float tx1 = truths[(b * N_ + n) * 4 + 0];
    float ty1 = truths[(b * N_ + n) * 4 + 1];
    float tx2 = truths[(b * N_ + n) * 4 + 2];
    float ty2 = truths[(b * N_ + n) * 4 + 3];

    unsigned long long best = 0ull;
    for (int p = threadIdx.x; p < P_; p += blockDim.x) {
        float4 pr = ((const float4*)priors)[p];
        float px1 = pr.x - pr.z * 0.5f, py1 = pr.y - pr.w * 0.5f;
        float px2 = pr.x + pr.z * 0.5f, py2 = pr.y + pr.w * 0.5f;
        float iou = iou_corner(tx1, ty1, tx2, ty2, px1, py1, px2, py2);
        unsigned long long key =
            ((unsigned long long)__float_as_uint(iou) << 32) | (unsigned)(~(unsigned)p);
        best = (key > best) ? key : best;
    }
    for (int off = 32; off; off >>= 1) {
        unsigned long long o = shfl_down_u64(best, off);
        best = (o > best) ? o : best;
    }
    __shared__ unsigned long long wbest[4];
    int wid = threadIdx.x >> 6, lane = threadIdx.x & 63;
    if (lane == 0) wbest[wid] = best;
    __syncthreads();
    if (threadIdx.x == 0) {
        int nw = blockDim.x >> 6;
        for (int i = 1; i < nw; i++) best = (wbest[i] > best) ? wbest[i] : best;
        bpi[b * N_ + n] = (int)(~(unsigned)(best & 0xFFFFFFFFull));
    }
}

// K4: sequential (last-wins) override: each truth keeps its best prior.
__global__ void k4_override(const int* __restrict__ bpi, uint8_t* __restrict__ match) {
    int b = threadIdx.x;
    if (b >= B_) return;
    for (int n = 0; n < N_; n++) {
        int p = bpi[b * N_ + n];
        match[(size_t)b * P_ + p] = (uint8_t)(n | 0x10);  // iou := 2.0 -> positive
    }
}

// K5: main loss: per-prior CE (logsumexp - gathered), loc smooth-L1 on
// positives, store loss_c_mine, count positives per batch.
__global__ void k5_loss(const float* __restrict__ loc,
                        const float* __restrict__ conf,
                        const float* __restrict__ priors,
                        const float* __restrict__ truths,
                        const int* __restrict__ labels,
                        const uint8_t* __restrict__ match,
                        float* __restrict__ mine,
                        int* __restrict__ numpos,
                        double* __restrict__ acc) {
    int b = blockIdx.y;
    int p = blockIdx.x * blockDim.x + threadIdx.x;
    __shared__ float tr[N_ * 4];
    __shared__ int lb[N_];
    if (threadIdx.x < N_ * 4) tr[threadIdx.x] = truths[b * N_ * 4 + threadIdx.x];
    if (threadIdx.x < N_) lb[threadIdx.x] = labels[b * N_ + threadIdx.x];
    __syncthreads();

    float ll = 0.0f, pce = 0.0f;
    int np = 0;
    if (p < P_) {
        uint8_t m = match[(size_t)b * P_ + p];
        int bti = m & 15;
        int pos = m >> 4;
        int cls = pos ? (lb[bti] + 1) : 0;

        const float* cp = conf + ((size_t)b * P_ + p) * C_;
        float xs[C_];
        float mx = -1e30f, g = 0.0f;
#pragma unroll
        for (int i = 0; i < C_; i++) {
            xs[i] = cp[i];
            mx = fmaxf(mx, xs[i]);
            if (i == cls) g = xs[i];  // select-chain, cls is runtime
        }
        float s = 0.0f;
#pragma unroll
        for (int i = 0; i < C_; i++) s += expf(xs[i] - mx);
        float lca = mx + logf(s) - g;  // >= 0 always

        mine[(size_t)b * P_ + p] = pos ? 0.0f : lca;

        if (pos) {
            np = 1;
            pce = lca;
            float4 pr = ((const float4*)priors)[p];
            float tx1 = tr[bti * 4 + 0], ty1 = tr[bti * 4 + 1];
            float tx2 = tr[bti * 4 + 2], ty2 = tr[bti * 4 + 3];
            float gcx = ((tx1 + tx2) * 0.5f - pr.x) / (0.1f * pr.z);
            float gcy = ((ty1 + ty2) * 0.5f - pr.y) / (0.1f * pr.w);
            float gw = logf((tx2 - tx1) / pr.z) / 0.2f;
            float gh = logf((ty2 - ty1) / pr.w) / 0.2f;
            float4 ld = ((const float4*)loc)[(size_t)b * P_ + p];
            float gt[4] = {gcx, gcy, gw, gh};
            float lv[4] = {ld.x, ld.y, ld.z, ld.w};
#pragma unroll
            for (int i = 0; i < 4; i++) {
                float d = lv[i] - gt[i];
                float ad = fabsf(d);
                ll += (ad < 1.0f) ? 0.5f * d * d : ad - 0.5f;
            }
        }
    }

    for (int off = 32; off; off >>= 1) {
        ll += __shfl_down(ll, off);
        pce += __shfl_down(pce, off);
        np += __shfl_down(np, off);
    }
    __shared__ float sll[4], spc[4];
    __shared__ int snp[4];
    int wid = threadIdx.x >> 6, lane = threadIdx.x & 63;
    if (lane == 0) { sll[wid] = ll; spc[wid] = pce; snp[wid] = np; }
    __syncthreads();
    if (threadIdx.x == 0) {
        float a = 0.0f, c = 0.0f;
        int q = 0;
        for (int i = 0; i < 4; i++) { a += sll[i]; c += spc[i]; q += snp[i]; }
        if (a != 0.0f) atomicAdd(&acc[0], (double)a);
        if (c != 0.0f) atomicAdd(&acc[1], (double)c);
        if (q) atomicAdd(&numpos[b], q);
    }
}

// K6: per-batch sum of top-k of loss_c_mine via 4-pass radix select on
// float bits (values are non-negative -> uint order == float order).
__global__ void k6_topk(const float* __restrict__ mine,
                        const int* __restrict__ numpos,
                        double* __restrict__ acc) {
    int b = blockIdx.x;
    const float* v = mine + (size_t)b * P_;
    int k = numpos[b] * 3;
    if (k > P_ - 1) k = P_ - 1;

    __shared__ unsigned cnt[256];
    __shared__ float bsum[256];
    __shared__ unsigned spfx, smsk;
    __shared__ int skrem;
    __shared__ double stot;
    if (threadIdx.x == 0) { spfx = 0u; smsk = 0u; skrem = k; stot = 0.0; }
    __syncthreads();

    for (int pass = 0; pass < 4; pass++) {
        int shift = 24 - 8 * pass;
        cnt[threadIdx.x] = 0u;
        bsum[threadIdx.x] = 0.0f;
        __syncthreads();
        unsigned pf = spfx, pm = smsk;
        for (int p = threadIdx.x; p < P_; p += blockDim.x) {
            float x = v[p];
            unsigned u = __float_as_uint(x);
            if ((u & pm) == pf) {
                unsigned bin = (u >> shift) & 255u;
                atomicAdd(&cnt[bin], 1u);
                atomicAdd(&bsum[bin], x);
            }
        }
        __syncthreads();
        if (threadIdx.x == 0) {
            int kr = skrem;
            unsigned c = 0;
            float sa = 0.0f;
            int bin;
            for (bin = 255; bin >= 0; bin--) {
                if ((int)(c + cnt[bin]) >= kr) break;
                c += cnt[bin];
                sa += bsum[bin];
            }
            if (bin < 0) bin = 0;  // defensive; invariant guarantees bin >= 0
            stot += (double)sa;
            skrem = kr - (int)c;
            spfx = pf | ((unsigned)bin << shift);
            smsk = pm | (0xFFu << shift);
        }
        __syncthreads();
    }
    if (threadIdx.x == 0) {
        float kv = __uint_as_float(spfx);  // exact k-th largest value
        double tot = stot + (double)skrem * (double)kv;
        atomicAdd(&acc[1], tot);
    }
}

// K7: finalize.
__global__ void k7_final(const int* __restrict__ numpos,
                         const double* __restrict__ acc,
                         float* __restrict__ out) {
    if (threadIdx.x == 0) {
        int n = 0;
        for (int b = 0; b < B_; b++) n += numpos[b];
        double dn = (double)n;
        out[0] = (float)(acc[0] / dn);
        out[1] = (float)(acc[1] / dn);
    }
}

// ---------------------------------------------------------------- launch

extern "C" void kernel_launch(void* const* d_in, const int* in_sizes, int n_in,
                              void* d_out, int out_size, void* d_ws, size_t ws_size,
                              hipStream_t stream) {
    const float* loc    = (const float*)d_in[0];
    const float* conf   = (const float*)d_in[1];
    const float* priors = (const float*)d_in[2];
    const float* truths = (const float*)d_in[3];
    const int*   labels = (const int*)d_in[4];
    float* out = (float*)d_out;

    char* ws = (char*)d_ws;
    // layout: [0..64)   2 doubles (acc: loss_l, loss_c)
    //         [64..320) 64 ints   (numpos per batch)
    //         [320..4416) 1024 ints (best prior idx per (b,n))
    //         [4416..1576512) B*P bytes (match byte)
    //         [1576512..7864896) B*P floats (loss_c_mine)
    double*  acc    = (double*)ws;
    int*     numpos = (int*)(ws + 64);
    int*     bpi    = (int*)(ws + 320);
    uint8_t* match  = (uint8_t*)(ws + 4416);
    float*   mine   = (float*)(ws + 1576512);

    dim3 blk(256);
    dim3 grid_pb((P_ + 255) / 256, B_);

    hipLaunchKernelGGL(k0_init, dim3(1), dim3(64), 0, stream, acc, numpos);
    hipLaunchKernelGGL(k2_match, grid_pb, blk, 0, stream, priors, truths, match);
    hipLaunchKernelGGL(k3_bestprior, dim3(B_ * N_), blk, 0, stream, priors, truths, bpi);
    hipLaunchKernelGGL(k4_override, dim3(1), dim3(64), 0, stream, bpi, match);
    hipLaunchKernelGGL(k5_loss, grid_pb, blk, 0, stream,
                       loc, conf, priors, truths, labels, match, mine, numpos, acc);
    hipLaunchKernelGGL(k6_topk, dim3(B_), blk, 0, stream, mine, numpos, acc);
    hipLaunchKernelGGL(k7_final, dim3(1), dim3(64), 0, stream, numpos, acc, out);
}

// Round 2
// 459.223 us; speedup vs baseline: 1.1603x; 1.1603x over previous
//
#include <hip/hip_runtime.h>
#include <cstdint>
#include <cstddef>

#define B_ 64
#define P_ 24564
#define C_ 21
#define N_ 16
#define THRESH_ 0.5f

// ---------------------------------------------------------------- helpers

__device__ inline unsigned long long shfl_down_u64(unsigned long long v, int off) {
    unsigned lo = (unsigned)(v & 0xFFFFFFFFull);
    unsigned hi = (unsigned)(v >> 32);
    lo = __shfl_down(lo, off);
    hi = __shfl_down(hi, off);
    return ((unsigned long long)hi << 32) | lo;
}

__device__ inline float iou_corner(float tx1, float ty1, float tx2, float ty2,
                                   float px1, float py1, float px2, float py2) {
    float lx = fmaxf(tx1, px1), ly = fmaxf(ty1, py1);
    float rx = fminf(tx2, px2), ry = fminf(ty2, py2);
    float w = fmaxf(rx - lx, 0.0f), h = fmaxf(ry - ly, 0.0f);
    float inter = w * h;
    float at = (tx2 - tx1) * (ty2 - ty1);
    float ap = (px2 - px1) * (py2 - py1);
    return inter / (at + ap - inter);
}

// ---------------------------------------------------------------- kernels

// K2: per (b,p) best truth over N=16 (first-max). Packed byte:
// low 4 bits = best_truth_idx, bit 4 = (iou >= 0.5).
// Block (0,0) also zeroes the global accumulators (k0 fold).
__global__ void k2_match(const float* __restrict__ priors,
                         const float* __restrict__ truths,
                         uint8_t* __restrict__ match,
                         double* __restrict__ acc,
                         int* __restrict__ numpos) {
    if (blockIdx.x == 0 && blockIdx.y == 0) {
        if (threadIdx.x < 2) acc[threadIdx.x] = 0.0;
        if (threadIdx.x >= 2 && threadIdx.x < 2 + B_) numpos[threadIdx.x - 2] = 0;
    }
    int b = blockIdx.y;
    int p = blockIdx.x * blockDim.x + threadIdx.x;
    __shared__ float tr[N_ * 4];
    if (threadIdx.x < N_ * 4) tr[threadIdx.x] = truths[b * N_ * 4 + threadIdx.x];
    __syncthreads();
    if (p >= P_) return;

    float4 pr = ((const float4*)priors)[p];
    float px1 = pr.x - pr.z * 0.5f, py1 = pr.y - pr.w * 0.5f;
    float px2 = pr.x + pr.z * 0.5f, py2 = pr.y + pr.w * 0.5f;

    float best = -1.0f;
    int bn = 0;
#pragma unroll
    for (int n = 0; n < N_; n++) {
        float iou = iou_corner(tr[n * 4 + 0], tr[n * 4 + 1], tr[n * 4 + 2], tr[n * 4 + 3],
                               px1, py1, px2, py2);
        if (iou > best) { best = iou; bn = n; }
    }
    match[(size_t)b * P_ + p] = (uint8_t)(bn | ((best < THRESH_) ? 0 : 0x10));
}

// K3: per (b,n) argmax over P priors (first-max -> smallest p).
__global__ void k3_bestprior(const float* __restrict__ priors,
                             const float* __restrict__ truths,
                             int* __restrict__ bpi) {
    int b = blockIdx.x / N_;
    int n = blockIdx.x % N_;
    float tx1 = truths[(b * N_ + n) * 4 + 0];
    float ty1 = truths[(b * N_ + n) * 4 + 1];
    float tx2 = truths[(b * N_ + n) * 4 + 2];
    float ty2 = truths[(b * N_ + n) * 4 + 3];

    unsigned long long best = 0ull;
    for (int p = threadIdx.x; p < P_; p += blockDim.x) {
        float4 pr = ((const float4*)priors)[p];
        float px1 = pr.x - pr.z * 0.5f, py1 = pr.y - pr.w * 0.5f;
        float px2 = pr.x + pr.z * 0.5f, py2 = pr.y + pr.w * 0.5f;
        float iou = iou_corner(tx1, ty1, tx2, ty2, px1, py1, px2, py2);
        unsigned long long key =
            ((unsigned long long)__float_as_uint(iou) << 32) | (unsigned)(~(unsigned)p);
        best = (key > best) ? key : best;
    }
    for (int off = 32; off; off >>= 1) {
        unsigned long long o = shfl_down_u64(best, off);
        best = (o > best) ? o : best;
    }
    __shared__ unsigned long long wbest[4];
    int wid = threadIdx.x >> 6, lane = threadIdx.x & 63;
    if (lane == 0) wbest[wid] = best;
    __syncthreads();
    if (threadIdx.x == 0) {
        int nw = blockDim.x >> 6;
        for (int i = 1; i < nw; i++) best = (wbest[i] > best) ? wbest[i] : best;
        bpi[b * N_ + n] = (int)(~(unsigned)(best & 0xFFFFFFFFull));
    }
}

// K5: main loss. Conf is staged through LDS with coalesced float4 loads;
// the best-prior override (old k4) is applied on the fly (highest n wins
// == sequential last-wins).
__global__ __launch_bounds__(256) void
k5_loss(const float* __restrict__ loc,
        const float* __restrict__ conf,
        const float* __restrict__ priors,
        const float* __restrict__ truths,
        const int* __restrict__ labels,
        const int* __restrict__ bpi,
        const uint8_t* __restrict__ match,
        float* __restrict__ mine,
        int* __restrict__ numpos,
        double* __restrict__ acc) {
    int b = blockIdx.y;
    int p0 = blockIdx.x * 256;
    int t = threadIdx.x;
    __shared__ float scf[256 * C_];       // 21504 B staged conf rows
    __shared__ float tr[N_ * 4];
    __shared__ int lb[N_];
    __shared__ int sbpi[N_];
    if (t < N_ * 4) tr[t] = truths[b * N_ * 4 + t];
    if (t < N_) { lb[t] = labels[b * N_ + t]; sbpi[t] = bpi[b * N_ + t]; }

    int nvalid = min(256, P_ - p0);
    int nf4 = (nvalid * C_) >> 2;         // 21*256 and 21*244 are both %4==0
    const float4* src = (const float4*)(conf + ((size_t)b * P_ + p0) * C_);
    float4* dst = (float4*)scf;
    for (int i = t; i < nf4; i += 256) dst[i] = src[i];
    __syncthreads();

    int p = p0 + t;
    float ll = 0.0f, pce = 0.0f;
    int np = 0;
    if (p < P_) {
        uint8_t m = match[(size_t)b * P_ + p];
        int bti = m & 15;
        int pos = m >> 4;
#pragma unroll
        for (int n = N_ - 1; n >= 0; n--) {   // highest n wins = last-wins
            if (sbpi[n] == p) { bti = n; pos = 1; break; }
        }
        int cls = pos ? (lb[bti] + 1) : 0;

        float xs[C_];
        float mx = -1e30f;
#pragma unroll
        for (int i = 0; i < C_; i++) {
            xs[i] = scf[t * C_ + i];
            mx = fmaxf(mx, xs[i]);
        }
        float s = 0.0f;
#pragma unroll
        for (int i = 0; i < C_; i++) s += expf(xs[i] - mx);
        float g = scf[t * C_ + cls];
        float lca = mx + logf(s) - g;     // >= 0 always

        mine[(size_t)b * P_ + p] = pos ? 0.0f : lca;

        if (pos) {
            np = 1;
            pce = lca;
            float4 pr = ((const float4*)priors)[p];
            float tx1 = tr[bti * 4 + 0], ty1 = tr[bti * 4 + 1];
            float tx2 = tr[bti * 4 + 2], ty2 = tr[bti * 4 + 3];
            float gcx = ((tx1 + tx2) * 0.5f - pr.x) / (0.1f * pr.z);
            float gcy = ((ty1 + ty2) * 0.5f - pr.y) / (0.1f * pr.w);
            float gw = logf((tx2 - tx1) / pr.z) / 0.2f;
            float gh = logf((ty2 - ty1) / pr.w) / 0.2f;
            float4 ld = ((const float4*)loc)[(size_t)b * P_ + p];
            float gt[4] = {gcx, gcy, gw, gh};
            float lv[4] = {ld.x, ld.y, ld.z, ld.w};
#pragma unroll
            for (int i = 0; i < 4; i++) {
                float d = lv[i] - gt[i];
                float ad = fabsf(d);
                ll += (ad < 1.0f) ? 0.5f * d * d : ad - 0.5f;
            }
        }
    }

    for (int off = 32; off; off >>= 1) {
        ll += __shfl_down(ll, off);
        pce += __shfl_down(pce, off);
        np += __shfl_down(np, off);
    }
    __shared__ float sll[4], spc[4];
    __shared__ int snp[4];
    int wid = t >> 6, lane = t & 63;
    if (lane == 0) { sll[wid] = ll; spc[wid] = pce; snp[wid] = np; }
    __syncthreads();
    if (t == 0) {
        float a = 0.0f, c = 0.0f;
        int q = 0;
        for (int i = 0; i < 4; i++) { a += sll[i]; c += spc[i]; q += snp[i]; }
        if (a != 0.0f) atomicAdd(&acc[0], (double)a);
        if (c != 0.0f) atomicAdd(&acc[1], (double)c);
        if (q) atomicAdd(&numpos[b], q);
    }
}

// K6: per-batch sum of top-k of loss_c_mine via 4-pass radix select.
// Counts-only histograms, privatized per wave (16 copies) to kill the
// same-address LDS-atomic serialization; final strict-greater sum pass.
__global__ __launch_bounds__(1024) void
k6_topk(const float* __restrict__ mine,
        const int* __restrict__ numpos,
        double* __restrict__ acc) {
    int b = blockIdx.x;
    const float* v = mine + (size_t)b * P_;
    int k = numpos[b] * 3;
    if (k > P_ - 1) k = P_ - 1;

    __shared__ unsigned cnt[16 * 256];
    __shared__ unsigned spfx;
    __shared__ int skrem;
    int t = threadIdx.x, wid = t >> 6;
    if (t == 0) { spfx = 0u; skrem = k; }

    for (int pass = 0; pass < 4; pass++) {
        for (int i = t; i < 16 * 256; i += 1024) cnt[i] = 0u;
        __syncthreads();
        unsigned pf = spfx;
        unsigned pm = pass ? (0xFFFFFFFFu << (32 - 8 * pass)) : 0u;
        int shift = 24 - 8 * pass;
        for (int p = t; p < P_; p += 1024) {
            unsigned u = __float_as_uint(v[p]);
            if ((u & pm) == pf) atomicAdd(&cnt[(wid << 8) + ((u >> shift) & 255u)], 1u);
        }
        __syncthreads();
        if (t < 256) {                     // column-wise copy reduction
            unsigned s = 0;
            for (int c = 0; c < 16; c++) s += cnt[(c << 8) + t];
            cnt[t] = s;
        }
        __syncthreads();
        if (t == 0) {
            int kr = skrem;
            unsigned c = 0;
            int bin;
            for (bin = 255; bin >= 0; bin--) {
                if ((int)(c + cnt[bin]) >= kr) break;
                c += cnt[bin];
            }
            if (bin < 0) bin = 0;          // defensive
            skrem = kr - (int)c;
            spfx = pf | ((unsigned)bin << shift);
        }
        __syncthreads();
    }

    unsigned thr = spfx;                   // exact k-th largest bit pattern
    float psum = 0.0f;
    for (int p = t; p < P_; p += 1024) {
        float x = v[p];
        if (__float_as_uint(x) > thr) psum += x;
    }
    for (int off = 32; off; off >>= 1) psum += __shfl_down(psum, off);
    __shared__ float wsum[16];
    if ((t & 63) == 0) wsum[wid] = psum;
    __syncthreads();
    if (t == 0) {
        float s = 0.0f;
        for (int i = 0; i < 16; i++) s += wsum[i];
        double tot = (double)s + (double)skrem * (double)__uint_as_float(thr);
        atomicAdd(&acc[1], tot);
    }
}

// K7: finalize.
__global__ void k7_final(const int* __restrict__ numpos,
                         const double* __restrict__ acc,
                         float* __restrict__ out) {
    if (threadIdx.x == 0) {
        int n = 0;
        for (int b = 0; b < B_; b++) n += numpos[b];
        double dn = (double)n;
        out[0] = (float)(acc[0] / dn);
        out[1] = (float)(acc[1] / dn);
    }
}

// ---------------------------------------------------------------- launch

extern "C" void kernel_launch(void* const* d_in, const int* in_sizes, int n_in,
                              void* d_out, int out_size, void* d_ws, size_t ws_size,
                              hipStream_t stream) {
    const float* loc    = (const float*)d_in[0];
    const float* conf   = (const float*)d_in[1];
    const float* priors = (const float*)d_in[2];
    const float* truths = (const float*)d_in[3];
    const int*   labels = (const int*)d_in[4];
    float* out = (float*)d_out;

    char* ws = (char*)d_ws;
    // layout: [0..64)        2 doubles (acc: loss_l, loss_c)
    //         [64..320)      64 ints   (numpos per batch)
    //         [320..4416)    1024 ints (best prior idx per (b,n))
    //         [4416..1576512)   B*P bytes  (match byte)
    //         [1576512..7864896) B*P floats (loss_c_mine)
    double*  acc    = (double*)ws;
    int*     numpos = (int*)(ws + 64);
    int*     bpi    = (int*)(ws + 320);
    uint8_t* match  = (uint8_t*)(ws + 4416);
    float*   mine   = (float*)(ws + 1576512);

    dim3 blk(256);
    dim3 grid_pb((P_ + 255) / 256, B_);

    hipLaunchKernelGGL(k2_match, grid_pb, blk, 0, stream, priors, truths, match, acc, numpos);
    hipLaunchKernelGGL(k3_bestprior, dim3(B_ * N_), blk, 0, stream, priors, truths, bpi);
    hipLaunchKernelGGL(k5_loss, grid_pb, blk, 0, stream,
                       loc, conf, priors, truths, labels, bpi, match, mine, numpos, acc);
    hipLaunchKernelGGL(k6_topk, dim3(B_), dim3(1024), 0, stream, mine, numpos, acc);
    hipLaunchKernelGGL(k7_final, dim3(1), dim3(64), 0, stream, numpos, acc, out);
}

// Round 3
// 363.055 us; speedup vs baseline: 1.4677x; 1.2649x over previous
//
#include <hip/hip_runtime.h>
#include <cstdint>
#include <cstddef>

#define B_ 64
#define P_ 24564
#define C_ 21
#define N_ 16
#define NPB_ 24          // k5 blocks per batch: 24*1024 = 24576 >= P_
#define THRESH_ 0.5f

// ---------------------------------------------------------------- helpers

__device__ inline unsigned long long shfl_down_u64(unsigned long long v, int off) {
    unsigned lo = (unsigned)(v & 0xFFFFFFFFull);
    unsigned hi = (unsigned)(v >> 32);
    lo = __shfl_down(lo, off);
    hi = __shfl_down(hi, off);
    return ((unsigned long long)hi << 32) | lo;
}

__device__ inline float iou_corner(float tx1, float ty1, float tx2, float ty2,
                                   float px1, float py1, float px2, float py2) {
    float lx = fmaxf(tx1, px1), ly = fmaxf(ty1, py1);
    float rx = fminf(tx2, px2), ry = fminf(ty2, py2);
    float w = fmaxf(rx - lx, 0.0f), h = fmaxf(ry - ly, 0.0f);
    float inter = w * h;
    float at = (tx2 - tx1) * (ty2 - ty1);
    float ap = (px2 - px1) * (py2 - py1);
    return inter / (at + ap - inter);
}

// ---------------------------------------------------------------- kernels

// K3: per (b,n) argmax over P priors (first-max -> smallest p).
__global__ void k3_bestprior(const float* __restrict__ priors,
                             const float* __restrict__ truths,
                             int* __restrict__ bpi) {
    int b = blockIdx.x / N_;
    int n = blockIdx.x % N_;
    float tx1 = truths[(b * N_ + n) * 4 + 0];
    float ty1 = truths[(b * N_ + n) * 4 + 1];
    float tx2 = truths[(b * N_ + n) * 4 + 2];
    float ty2 = truths[(b * N_ + n) * 4 + 3];

    unsigned long long best = 0ull;
    for (int p = threadIdx.x; p < P_; p += blockDim.x) {
        float4 pr = ((const float4*)priors)[p];
        float px1 = pr.x - pr.z * 0.5f, py1 = pr.y - pr.w * 0.5f;
        float px2 = pr.x + pr.z * 0.5f, py2 = pr.y + pr.w * 0.5f;
        float iou = iou_corner(tx1, ty1, tx2, ty2, px1, py1, px2, py2);
        unsigned long long key =
            ((unsigned long long)__float_as_uint(iou) << 32) | (unsigned)(~(unsigned)p);
        best = (key > best) ? key : best;
    }
    for (int off = 32; off; off >>= 1) {
        unsigned long long o = shfl_down_u64(best, off);
        best = (o > best) ? o : best;
    }
    __shared__ unsigned long long wbest[4];
    int wid = threadIdx.x >> 6, lane = threadIdx.x & 63;
    if (lane == 0) wbest[wid] = best;
    __syncthreads();
    if (threadIdx.x == 0) {
        int nw = blockDim.x >> 6;
        for (int i = 1; i < nw; i++) best = (wbest[i] > best) ? wbest[i] : best;
        bpi[b * N_ + n] = (int)(~(unsigned)(best & 0xFFFFFFFFull));
    }
}

// K5: fused match + loss. Thread owns 4 consecutive priors: 21 independent
// float4 loads (register-resident rows, deep MLP), inline best-truth match,
// LSE/CE, smooth-L1, coalesced float4 mine store. NO atomics: per-block
// partials to plain arrays.
__global__ __launch_bounds__(256) void
k5_fused(const float* __restrict__ loc,
         const float* __restrict__ conf,
         const float* __restrict__ priors,
         const float* __restrict__ truths,
         const int* __restrict__ labels,
         const int* __restrict__ bpi,
         float* __restrict__ mine,
         float* __restrict__ part_ll,
         float* __restrict__ part_pce,
         int* __restrict__ part_np) {
    int b = blockIdx.y;
    int bx = blockIdx.x;
    int t = threadIdx.x;
    __shared__ float tr[N_ * 4];
    __shared__ int lb[N_];
    __shared__ int sbpi[N_];
    if (t < N_ * 4) tr[t] = truths[b * N_ * 4 + t];
    if (t < N_) { lb[t] = labels[b * N_ + t]; sbpi[t] = bpi[b * N_ + t]; }
    __syncthreads();

    int p0 = bx * 1024 + 4 * t;          // this thread's first prior
    float ll = 0.0f, pce = 0.0f;
    int np = 0;

    if (p0 < P_) {                        // P_ % 4 == 0: all-or-nothing per thread
        // ---- load 4 conf rows (84 floats) as 21 aligned float4 ----
        float c[84];
        float4* cv = (float4*)c;
        const float4* src = (const float4*)(conf + ((size_t)b * P_ + (size_t)bx * 1024) * C_);
#pragma unroll
        for (int i = 0; i < 21; i++) cv[i] = src[t * 21 + i];

        // ---- prior boxes ----
        float4 pr[4];
#pragma unroll
        for (int r = 0; r < 4; r++) pr[r] = ((const float4*)priors)[p0 + r];

        // ---- inline k2: best truth per prior (first-max) ----
        float best[4] = {-1.0f, -1.0f, -1.0f, -1.0f};
        int bn[4] = {0, 0, 0, 0};
#pragma unroll
        for (int n = 0; n < N_; n++) {
            float tx1 = tr[n * 4 + 0], ty1 = tr[n * 4 + 1];
            float tx2 = tr[n * 4 + 2], ty2 = tr[n * 4 + 3];
            float at = (tx2 - tx1) * (ty2 - ty1);
#pragma unroll
            for (int r = 0; r < 4; r++) {
                float px1 = pr[r].x - pr[r].z * 0.5f, py1 = pr[r].y - pr[r].w * 0.5f;
                float px2 = pr[r].x + pr[r].z * 0.5f, py2 = pr[r].y + pr[r].w * 0.5f;
                float lx = fmaxf(tx1, px1), ly = fmaxf(ty1, py1);
                float rx = fminf(tx2, px2), ry = fminf(ty2, py2);
                float w = fmaxf(rx - lx, 0.0f), h = fmaxf(ry - ly, 0.0f);
                float inter = w * h;
                float ap = (px2 - px1) * (py2 - py1);
                float iou = inter / (at + ap - inter);
                if (iou > best[r]) { best[r] = iou; bn[r] = n; }
            }
        }

        float mv[4];
#pragma unroll
        for (int r = 0; r < 4; r++) {
            int p = p0 + r;
            int bti = bn[r];
            int pos = (best[r] < THRESH_) ? 0 : 1;
#pragma unroll
            for (int n = N_ - 1; n >= 0; n--) {   // highest n wins = last-wins
                if (sbpi[n] == p) { bti = n; pos = 1; break; }
            }
            int cls = pos ? (lb[bti] + 1) : 0;

            float mx = -1e30f, g = 0.0f;
#pragma unroll
            for (int j = 0; j < C_; j++) {
                float x = c[21 * r + j];
                mx = fmaxf(mx, x);
                if (j == cls) g = x;              // cndmask chain (runtime cls)
            }
            float s = 0.0f;
#pragma unroll
            for (int j = 0; j < C_; j++) s += expf(c[21 * r + j] - mx);
            float lca = mx + logf(s) - g;         // >= 0 always

            mv[r] = pos ? 0.0f : lca;

            if (pos) {
                np++;
                pce += lca;
                float tx1 = tr[bti * 4 + 0], ty1 = tr[bti * 4 + 1];
                float tx2 = tr[bti * 4 + 2], ty2 = tr[bti * 4 + 3];
                float gcx = ((tx1 + tx2) * 0.5f - pr[r].x) / (0.1f * pr[r].z);
                float gcy = ((ty1 + ty2) * 0.5f - pr[r].y) / (0.1f * pr[r].w);
                float gw = logf((tx2 - tx1) / pr[r].z) / 0.2f;
                float gh = logf((ty2 - ty1) / pr[r].w) / 0.2f;
                float4 ld = ((const float4*)loc)[(size_t)b * P_ + p];
                float gt[4] = {gcx, gcy, gw, gh};
                float lv[4] = {ld.x, ld.y, ld.z, ld.w};
#pragma unroll
                for (int i = 0; i < 4; i++) {
                    float d = lv[i] - gt[i];
                    float ad = fabsf(d);
                    ll += (ad < 1.0f) ? 0.5f * d * d : ad - 0.5f;
                }
            }
        }
        *(float4*)(mine + (size_t)b * P_ + p0) = make_float4(mv[0], mv[1], mv[2], mv[3]);
    }

    // ---- block reduction, no atomics ----
    for (int off = 32; off; off >>= 1) {
        ll += __shfl_down(ll, off);
        pce += __shfl_down(pce, off);
        np += __shfl_down(np, off);
    }
    __shared__ float sll[4], spc[4];
    __shared__ int snp[4];
    int wid = t >> 6, lane = t & 63;
    if (lane == 0) { sll[wid] = ll; spc[wid] = pce; snp[wid] = np; }
    __syncthreads();
    if (t == 0) {
        float a = 0.0f, cc = 0.0f;
        int q = 0;
        for (int i = 0; i < 4; i++) { a += sll[i]; cc += spc[i]; q += snp[i]; }
        part_ll[b * NPB_ + bx] = a;
        part_pce[b * NPB_ + bx] = cc;
        part_np[b * NPB_ + bx] = q;
    }
}

// K6: per-batch sum of top-k of loss_c_mine via 4-pass radix select on float
// bits. Per-wave privatized count histograms; final strict-greater sum pass.
// num_pos derived from part_np; result written (no atomics).
__global__ __launch_bounds__(1024) void
k6_topk(const float* __restrict__ mine,
        const int* __restrict__ part_np,
        double* __restrict__ topk) {
    int b = blockIdx.x;
    const float* v = mine + (size_t)b * P_;
    int t = threadIdx.x, wid = t >> 6;

    __shared__ unsigned cnt[16 * 256];
    __shared__ unsigned spfx;
    __shared__ int skrem;
    if (t == 0) {
        int s = 0;
        for (int i = 0; i < NPB_; i++) s += part_np[b * NPB_ + i];
        int k = s * 3;
        if (k > P_ - 1) k = P_ - 1;
        spfx = 0u;
        skrem = k;
    }

    for (int pass = 0; pass < 4; pass++) {
        for (int i = t; i < 16 * 256; i += 1024) cnt[i] = 0u;
        __syncthreads();
        unsigned pf = spfx;
        unsigned pm = pass ? (0xFFFFFFFFu << (32 - 8 * pass)) : 0u;
        int shift = 24 - 8 * pass;
        for (int p = t; p < P_; p += 1024) {
            unsigned u = __float_as_uint(v[p]);
            if ((u & pm) == pf) atomicAdd(&cnt[(wid << 8) + ((u >> shift) & 255u)], 1u);
        }
        __syncthreads();
        if (t < 256) {
            unsigned s = 0;
            for (int c = 0; c < 16; c++) s += cnt[(c << 8) + t];
            cnt[t] = s;
        }
        __syncthreads();
        if (t == 0) {
            int kr = skrem;
            unsigned c = 0;
            int bin;
            for (bin = 255; bin >= 0; bin--) {
                if ((int)(c + cnt[bin]) >= kr) break;
                c += cnt[bin];
            }
            if (bin < 0) bin = 0;          // defensive
            skrem = kr - (int)c;
            spfx = pf | ((unsigned)bin << shift);
        }
        __syncthreads();
    }

    unsigned thr = spfx;                   // k-th largest bit pattern
    float psum = 0.0f;
    for (int p = t; p < P_; p += 1024) {
        float x = v[p];
        if (__float_as_uint(x) > thr) psum += x;
    }
    for (int off = 32; off; off >>= 1) psum += __shfl_down(psum, off);
    __shared__ float wsum[16];
    if ((t & 63) == 0) wsum[wid] = psum;
    __syncthreads();
    if (t == 0) {
        float s = 0.0f;
        for (int i = 0; i < 16; i++) s += wsum[i];
        topk[b] = (double)s + (double)skrem * (double)__uint_as_float(thr);
    }
}

// K7: final reduction of all partials.
__global__ __launch_bounds__(256) void
k7_final(const float* __restrict__ part_ll,
         const float* __restrict__ part_pce,
         const int* __restrict__ part_np,
         const double* __restrict__ topk,
         float* __restrict__ out) {
    int t = threadIdx.x;
    double ll = 0.0, pc = 0.0;
    int np = 0;
    for (int i = t; i < B_ * NPB_; i += 256) {
        ll += (double)part_ll[i];
        pc += (double)part_pce[i];
        np += part_np[i];
    }
    if (t < B_) pc += topk[t];
    for (int off = 32; off; off >>= 1) {
        ll += __shfl_down(ll, off);
        pc += __shfl_down(pc, off);
        np += __shfl_down(np, off);
    }
    __shared__ double sll[4], spc[4];
    __shared__ int snp[4];
    int wid = t >> 6, lane = t & 63;
    if (lane == 0) { sll[wid] = ll; spc[wid] = pc; snp[wid] = np; }
    __syncthreads();
    if (t == 0) {
        double a = 0.0, c = 0.0;
        int n = 0;
        for (int i = 0; i < 4; i++) { a += sll[i]; c += spc[i]; n += snp[i]; }
        double dn = (double)n;
        out[0] = (float)(a / dn);
        out[1] = (float)(c / dn);
    }
}

// ---------------------------------------------------------------- launch

extern "C" void kernel_launch(void* const* d_in, const int* in_sizes, int n_in,
                              void* d_out, int out_size, void* d_ws, size_t ws_size,
                              hipStream_t stream) {
    const float* loc    = (const float*)d_in[0];
    const float* conf   = (const float*)d_in[1];
    const float* priors = (const float*)d_in[2];
    const float* truths = (const float*)d_in[3];
    const int*   labels = (const int*)d_in[4];
    float* out = (float*)d_out;

    char* ws = (char*)d_ws;
    // layout:
    //   [0      .. 4096 )  bpi: 1024 ints
    //   [4096   .. 10240)  part_ll: 1536 floats
    //   [10240  .. 16384)  part_pce: 1536 floats
    //   [16384  .. 22528)  part_np: 1536 ints
    //   [22528  .. 23040)  topk: 64 doubles
    //   [24576  .. 24576 + B*P*4)  mine: B*P floats (~6.29 MB)
    int*    bpi      = (int*)(ws);
    float*  part_ll  = (float*)(ws + 4096);
    float*  part_pce = (float*)(ws + 10240);
    int*    part_np  = (int*)(ws + 16384);
    double* topk     = (double*)(ws + 22528);
    float*  mine     = (float*)(ws + 24576);

    hipLaunchKernelGGL(k3_bestprior, dim3(B_ * N_), dim3(256), 0, stream,
                       priors, truths, bpi);
    hipLaunchKernelGGL(k5_fused, dim3(NPB_, B_), dim3(256), 0, stream,
                       loc, conf, priors, truths, labels, bpi,
                       mine, part_ll, part_pce, part_np);
    hipLaunchKernelGGL(k6_topk, dim3(B_), dim3(1024), 0, stream,
                       mine, part_np, topk);
    hipLaunchKernelGGL(k7_final, dim3(1), dim3(256), 0, stream,
                       part_ll, part_pce, part_np, topk, out);
}